// Round 4
// baseline (898.501 us; speedup 1.0000x reference)
//
#include <hip/hip_runtime.h>

typedef __bf16 bf16_t;
typedef __bf16 bf16x8 __attribute__((ext_vector_type(8)));
typedef float f32x4 __attribute__((ext_vector_type(4)));

#define N_NODES 50000
#define N_PAD   50048   // padded to multiple of 128 for 128-row GEMM tiles
#define N_EDGES 400000
#define D_IN    256
#define D_HID   512
#define D_OUT   128
#define N_LAYERS 4

#define AS1 __attribute__((address_space(1)))
#define AS3 __attribute__((address_space(3)))

static __device__ __forceinline__ float bf16_bits_to_f32(unsigned short u) {
    return __uint_as_float(((unsigned int)u) << 16);
}

// ---------------- fp32 -> bf16 conversion (flat, for x) ----------------

__global__ void f32_to_bf16(const float* __restrict__ in, bf16_t* __restrict__ out, int n) {
    int idx = (blockIdx.x * blockDim.x + threadIdx.x) * 4;
    if (idx + 3 < n) {
        float4 v = *reinterpret_cast<const float4*>(in + idx);
        bf16_t o[4] = {(bf16_t)v.x, (bf16_t)v.y, (bf16_t)v.z, (bf16_t)v.w};
        *reinterpret_cast<uint2*>(out + idx) = *reinterpret_cast<const uint2*>(o);
    } else {
        for (int j = idx; j < n; j++) out[j] = (bf16_t)in[j];
    }
}

// ---------------- fp32 [R][C] -> bf16 transposed [C][R] (for weights) ----------------

__global__ void transpose_to_bf16(const float* __restrict__ in, bf16_t* __restrict__ out,
                                  int R, int C) {
    __shared__ float tile[32][33];
    const int c0 = blockIdx.x * 32;
    const int r0 = blockIdx.y * 32;
    for (int i = threadIdx.y; i < 32; i += 8)
        tile[i][threadIdx.x] = in[(size_t)(r0 + i) * C + c0 + threadIdx.x];
    __syncthreads();
    for (int i = threadIdx.y; i < 32; i += 8)
        out[(size_t)(c0 + i) * R + r0 + threadIdx.x] = (bf16_t)tile[threadIdx.x][i];
}

// ---------------- degree / CSR build ----------------

__global__ void count_deg(const int* __restrict__ dst, int* __restrict__ deg, int E) {
    int e = blockIdx.x * blockDim.x + threadIdx.x;
    if (e < E) atomicAdd(&deg[dst[e]], 1);
}

__global__ void scan_reduce(const int* __restrict__ deg, int* __restrict__ partial, int N) {
    __shared__ int red[256];
    int base = blockIdx.x * 1024;
    int s = 0;
    for (int i = threadIdx.x; i < 1024; i += 256) {
        int idx = base + i;
        s += (idx < N) ? deg[idx] : 0;
    }
    red[threadIdx.x] = s;
    __syncthreads();
    for (int off = 128; off > 0; off >>= 1) {
        if (threadIdx.x < off) red[threadIdx.x] += red[threadIdx.x + off];
        __syncthreads();
    }
    if (threadIdx.x == 0) partial[blockIdx.x] = red[0];
}

__global__ void scan_partials(int* __restrict__ partial, int nb,
                              int* __restrict__ row_start, int N, int E) {
    if (threadIdx.x == 0 && blockIdx.x == 0) {
        int acc = 0;
        for (int i = 0; i < nb; i++) { int v = partial[i]; partial[i] = acc; acc += v; }
        row_start[N] = E;
    }
}

__global__ void scan_chunks(const int* __restrict__ deg, const int* __restrict__ partial,
                            int* __restrict__ row_start, int N) {
    __shared__ int buf[2][1024];
    int t = threadIdx.x;
    int gid = blockIdx.x * 1024 + t;
    int v = (gid < N) ? deg[gid] : 0;
    int cur = 0;
    buf[0][t] = v;
    __syncthreads();
    for (int off = 1; off < 1024; off <<= 1) {
        int nxt = cur ^ 1;
        int val = buf[cur][t];
        if (t >= off) val += buf[cur][t - off];
        buf[nxt][t] = val;
        cur = nxt;
        __syncthreads();
    }
    int incl = buf[cur][t];
    if (gid < N) row_start[gid] = partial[blockIdx.x] + incl - v;  // exclusive
}

__global__ void compute_dinv(const int* __restrict__ deg, float* __restrict__ dinv, int N) {
    int n = blockIdx.x * blockDim.x + threadIdx.x;
    if (n < N) dinv[n] = rsqrtf((float)(deg[n] + 1));  // +1 self loop
}

__global__ void fill_csr(const int* __restrict__ ei, int E,
                         const int* __restrict__ row_start,
                         int* __restrict__ cursor, int* __restrict__ csr_src) {
    int e = blockIdx.x * blockDim.x + threadIdx.x;
    if (e < E) {
        int s = ei[e];
        int d = ei[E + e];
        int pos = atomicAdd(&cursor[d], 1);
        csr_src[row_start[d] + pos] = s;
    }
}

// ---------------- GEMM (m97 structure): C = act(rowscale * (A @ BT^T) + bias) ----------------
// A: [M_pad][K] bf16. BT: [N][K] bf16 (pre-transposed). 128x128 tile, 4 waves x 64x64,
// BK=32, global_load_lds width=16 staging.

template <bool F32OUT, bool RELU>
__global__ __launch_bounds__(256) void gemm128(
    const bf16_t* __restrict__ A, const bf16_t* __restrict__ BT,
    const float* __restrict__ bias, const float* __restrict__ rowscale,
    void* __restrict__ Cv, int M, int N, int K)
{
    __shared__ __align__(16) bf16_t sA[128 * 32];
    __shared__ __align__(16) bf16_t sB[128 * 32];

    const int tid  = threadIdx.x;
    const int lane = tid & 63;
    const int wave = tid >> 6;
    const int bn = blockIdx.x * 128;
    const int bm = blockIdx.y * 128;
    const int wm = (wave & 1) * 64;
    const int wn = (wave >> 1) * 64;
    const int lm = lane & 15;
    const int lq = lane >> 4;

    const int r4 = lane >> 2;          // row within 16-row group
    const int kq = (lane & 3) * 8;     // k offset (elements)

    f32x4 acc[4][4] = {};

    const int nkb = K >> 5;
    for (int kb = 0; kb < nkb; kb++) {
        const int k0 = kb * 32;
#pragma unroll
        for (int r = 0; r < 2; r++) {
            const int g = r * 4 + wave;              // 16-row group 0..7
            const int row = g * 16 + r4;
            __builtin_amdgcn_global_load_lds(
                (const AS1 unsigned int*)(A + (size_t)(bm + row) * K + k0 + kq),
                (AS3 unsigned int*)((AS3 char*)(AS3 bf16_t*)sA + g * 1024),
                16, 0, 0);
            __builtin_amdgcn_global_load_lds(
                (const AS1 unsigned int*)(BT + (size_t)(bn + row) * K + k0 + kq),
                (AS3 unsigned int*)((AS3 char*)(AS3 bf16_t*)sB + g * 1024),
                16, 0, 0);
        }
        __syncthreads();

        bf16x8 af[4], bf[4];
#pragma unroll
        for (int mt = 0; mt < 4; mt++)
            af[mt] = *reinterpret_cast<bf16x8*>(&sA[(wm + mt * 16 + lm) * 32 + lq * 8]);
#pragma unroll
        for (int nt = 0; nt < 4; nt++)
            bf[nt] = *reinterpret_cast<bf16x8*>(&sB[(wn + nt * 16 + lm) * 32 + lq * 8]);
#pragma unroll
        for (int mt = 0; mt < 4; mt++)
#pragma unroll
            for (int nt = 0; nt < 4; nt++)
                acc[mt][nt] = __builtin_amdgcn_mfma_f32_16x16x32_bf16(af[mt], bf[nt], acc[mt][nt], 0, 0, 0);
        __syncthreads();
    }

    // epilogue: C/D layout col=lane&15, row=lq*4+reg
#pragma unroll
    for (int nt = 0; nt < 4; nt++) {
        const int col = bn + wn + nt * 16 + lm;
        const float bv = bias ? bias[col] : 0.0f;
#pragma unroll
        for (int mt = 0; mt < 4; mt++) {
#pragma unroll
            for (int r = 0; r < 4; r++) {
                const int row = bm + wm + mt * 16 + lq * 4 + r;
                if (row < M) {
                    float v = acc[mt][nt][r] + bv;
                    if (rowscale) v *= rowscale[row];
                    if (RELU) v = fmaxf(v, 0.0f);
                    if (F32OUT) ((float*)Cv)[(size_t)row * N + col] = v;
                    else        ((bf16_t*)Cv)[(size_t)row * N + col] = (bf16_t)v;
                }
            }
        }
    }
}

// ---------------- aggregation ----------------
// hw is pre-scaled: hw[s] = dinv[s] * (h W)[s].
// h_out[n] = dinv[n] * ( hw[n] + sum_{s->n} hw[s] ) + bias
// one wave per node; lane handles 8 contiguous features (512 = 64*8).
// Edge loop chunked by 4: one scalar index fetch + 4 independent 16B gathers in flight.

__global__ __launch_bounds__(256) void aggregate(
    const bf16_t* __restrict__ hw, const float* __restrict__ dinv,
    const int* __restrict__ row_start, const int* __restrict__ csr_src,
    const float* __restrict__ bias, bf16_t* __restrict__ h_out, int N)
{
    const int n = blockIdx.x * 4 + (threadIdx.x >> 6);
    const int lane = threadIdx.x & 63;
    if (n >= N) return;

    const float dn = dinv[n];
    const int f = lane * 8;

    float acc[8];
    {   // self term (already scaled by dinv[n])
        uint4 u = *reinterpret_cast<const uint4*>(hw + (size_t)n * D_HID + f);
        const unsigned short* hv = reinterpret_cast<const unsigned short*>(&u);
#pragma unroll
        for (int j = 0; j < 8; j++) acc[j] = bf16_bits_to_f32(hv[j]);
    }

    const int beg = row_start[n];
    const int cnt = row_start[n + 1] - beg;

    int i = 0;
    for (; i + 4 <= cnt; i += 4) {
        const int s0 = csr_src[beg + i];
        const int s1 = csr_src[beg + i + 1];
        const int s2 = csr_src[beg + i + 2];
        const int s3 = csr_src[beg + i + 3];
        uint4 u0 = *reinterpret_cast<const uint4*>(hw + (size_t)s0 * D_HID + f);
        uint4 u1 = *reinterpret_cast<const uint4*>(hw + (size_t)s1 * D_HID + f);
        uint4 u2 = *reinterpret_cast<const uint4*>(hw + (size_t)s2 * D_HID + f);
        uint4 u3 = *reinterpret_cast<const uint4*>(hw + (size_t)s3 * D_HID + f);
        const unsigned short* h0 = reinterpret_cast<const unsigned short*>(&u0);
        const unsigned short* h1 = reinterpret_cast<const unsigned short*>(&u1);
        const unsigned short* h2 = reinterpret_cast<const unsigned short*>(&u2);
        const unsigned short* h3 = reinterpret_cast<const unsigned short*>(&u3);
#pragma unroll
        for (int j = 0; j < 8; j++) {
            float t0 = bf16_bits_to_f32(h0[j]) + bf16_bits_to_f32(h1[j]);
            float t1 = bf16_bits_to_f32(h2[j]) + bf16_bits_to_f32(h3[j]);
            acc[j] += t0 + t1;
        }
    }
    // remainder (0..3 edges), 2-deep pipeline
    if (i < cnt) {
        int s0 = csr_src[beg + i];
        uint4 u0 = *reinterpret_cast<const uint4*>(hw + (size_t)s0 * D_HID + f);
        for (; i < cnt; ) {
            i++;
            uint4 u1;
            if (i < cnt) {
                int s1 = csr_src[beg + i];
                u1 = *reinterpret_cast<const uint4*>(hw + (size_t)s1 * D_HID + f);
            }
            const unsigned short* hv = reinterpret_cast<const unsigned short*>(&u0);
#pragma unroll
            for (int j = 0; j < 8; j++) acc[j] += bf16_bits_to_f32(hv[j]);
            u0 = u1;
        }
    }

    bf16_t outv[8];
#pragma unroll
    for (int j = 0; j < 8; j++) outv[j] = (bf16_t)(fmaf(dn, acc[j], bias[f + j]));
    *reinterpret_cast<uint4*>(h_out + (size_t)n * D_HID + f) = *reinterpret_cast<const uint4*>(outv);
}

// ---------------- orchestration ----------------

extern "C" void kernel_launch(void* const* d_in, const int* in_sizes, int n_in,
                              void* d_out, int out_size, void* d_ws, size_t ws_size,
                              hipStream_t stream) {
    const int N = N_NODES, E = N_EDGES;

    const float* x  = (const float*)d_in[0];
    const int*   ei = (const int*)d_in[1];
    const float* W1 = (const float*)d_in[2];
    const float* b1 = (const float*)d_in[3];
    const float* Wc = (const float*)d_in[4];
    const float* bc = (const float*)d_in[5];
    const float* W2 = (const float*)d_in[6];
    const float* b2 = (const float*)d_in[7];
    float* out = (float*)d_out;

    char* ws = (char*)d_ws;
    size_t off = 0;
    auto alloc = [&](size_t bytes) -> void* {
        void* p = ws + off;
        off += (bytes + 255) & ~(size_t)255;
        return p;
    };
    int*    deg       = (int*)alloc((size_t)N * 4);
    int*    cursor    = (int*)alloc((size_t)N * 4);
    int*    row_start = (int*)alloc((size_t)(N + 1) * 4);
    int*    partial   = (int*)alloc(256 * 4);
    float*  dinv      = (float*)alloc((size_t)N * 4);
    int*    csr_src   = (int*)alloc((size_t)E * 4);
    bf16_t* h         = (bf16_t*)alloc((size_t)N_PAD * D_HID * 2);
    bf16_t* hw        = (bf16_t*)alloc((size_t)N_PAD * D_HID * 2);
    bf16_t* xb        = (bf16_t*)alloc((size_t)N_PAD * D_IN * 2);
    bf16_t* W1t       = (bf16_t*)alloc((size_t)D_HID * D_IN * 2);
    bf16_t* Wct       = (bf16_t*)alloc((size_t)N_LAYERS * D_HID * D_HID * 2);
    bf16_t* W2t       = (bf16_t*)alloc((size_t)D_OUT * D_HID * 2);

    hipMemsetAsync(deg, 0, (size_t)N * 4, stream);
    hipMemsetAsync(cursor, 0, (size_t)N * 4, stream);

    // conversions: x flat; weights transposed to [N][K]
    {
        int n = N * D_IN;
        f32_to_bf16<<<(n / 4 + 255) / 256, 256, 0, stream>>>(x, xb, n);
        dim3 tb(32, 8);
        transpose_to_bf16<<<dim3(D_HID / 32, D_IN / 32), tb, 0, stream>>>(W1, W1t, D_IN, D_HID);
        for (int i = 0; i < N_LAYERS; i++)
            transpose_to_bf16<<<dim3(D_HID / 32, D_HID / 32), tb, 0, stream>>>(
                Wc + (size_t)i * D_HID * D_HID, Wct + (size_t)i * D_HID * D_HID, D_HID, D_HID);
        transpose_to_bf16<<<dim3(D_OUT / 32, D_HID / 32), tb, 0, stream>>>(W2, W2t, D_HID, D_OUT);
    }

    // CSR build
    count_deg<<<(E + 255) / 256, 256, 0, stream>>>(ei + E, deg, E);
    const int nch = (N + 1023) / 1024;
    scan_reduce<<<nch, 256, 0, stream>>>(deg, partial, N);
    scan_partials<<<1, 64, 0, stream>>>(partial, nch, row_start, N, E);
    scan_chunks<<<nch, 1024, 0, stream>>>(deg, partial, row_start, N);
    compute_dinv<<<(N + 255) / 256, 256, 0, stream>>>(deg, dinv, N);
    fill_csr<<<(E + 255) / 256, 256, 0, stream>>>(ei, E, row_start, cursor, csr_src);

    const dim3 blk(256);
    const int mg = N_PAD / 128;  // 391

    // dnn1: h = relu(x @ W1 + b1)
    gemm128<false, true><<<dim3(D_HID / 128, mg), blk, 0, stream>>>(
        xb, W1t, b1, nullptr, h, N, D_HID, D_IN);

    // GCN layers: hw = dinv .* (h @ Wc[i]); h = dinv .* (hw[self] + gather-sum) + bc[i]
    for (int i = 0; i < N_LAYERS; i++) {
        gemm128<false, false><<<dim3(D_HID / 128, mg), blk, 0, stream>>>(
            h, Wct + (size_t)i * D_HID * D_HID, nullptr, dinv, hw, N, D_HID, D_HID);
        aggregate<<<(N + 3) / 4, 256, 0, stream>>>(hw, dinv, row_start, csr_src,
                                                   bc + (size_t)i * D_HID, h, N);
    }

    // dnn2: out = h @ W2 + b2 (fp32 out)
    gemm128<true, false><<<dim3(D_OUT / 128, mg), blk, 0, stream>>>(
        h, W2t, b2, nullptr, out, N, D_OUT, D_HID);
}

// Round 5
// 853.480 us; speedup vs baseline: 1.0527x; 1.0527x over previous
//
#include <hip/hip_runtime.h>

typedef __bf16 bf16_t;
typedef __bf16 bf16x8 __attribute__((ext_vector_type(8)));
typedef float f32x4 __attribute__((ext_vector_type(4)));

#define N_NODES 50000
#define N_PAD   50048   // padded to multiple of 128 for 128-row GEMM tiles
#define N_EDGES 400000
#define D_IN    256
#define D_HID   512
#define D_OUT   128
#define N_LAYERS 4

#define AS1 __attribute__((address_space(1)))
#define AS3 __attribute__((address_space(3)))

static __device__ __forceinline__ float bf16_bits_to_f32(unsigned short u) {
    return __uint_as_float(((unsigned int)u) << 16);
}

// ---------------- fp32 -> bf16 conversion (flat, for x) ----------------

__global__ void f32_to_bf16(const float* __restrict__ in, bf16_t* __restrict__ out, int n) {
    int idx = (blockIdx.x * blockDim.x + threadIdx.x) * 4;
    if (idx + 3 < n) {
        float4 v = *reinterpret_cast<const float4*>(in + idx);
        bf16_t o[4] = {(bf16_t)v.x, (bf16_t)v.y, (bf16_t)v.z, (bf16_t)v.w};
        *reinterpret_cast<uint2*>(out + idx) = *reinterpret_cast<const uint2*>(o);
    } else {
        for (int j = idx; j < n; j++) out[j] = (bf16_t)in[j];
    }
}

// ---------------- fp32 [R][C] -> bf16 transposed [C][R] (for weights) ----------------

__global__ void transpose_to_bf16(const float* __restrict__ in, bf16_t* __restrict__ out,
                                  int R, int C) {
    __shared__ float tile[32][33];
    const int c0 = blockIdx.x * 32;
    const int r0 = blockIdx.y * 32;
    for (int i = threadIdx.y; i < 32; i += 8)
        tile[i][threadIdx.x] = in[(size_t)(r0 + i) * C + c0 + threadIdx.x];
    __syncthreads();
    for (int i = threadIdx.y; i < 32; i += 8)
        out[(size_t)(c0 + i) * R + r0 + threadIdx.x] = (bf16_t)tile[threadIdx.x][i];
}

// ---------------- degree / CSR build ----------------

__global__ void count_deg(const int* __restrict__ dst, int* __restrict__ deg, int E) {
    int e = blockIdx.x * blockDim.x + threadIdx.x;
    if (e < E) atomicAdd(&deg[dst[e]], 1);
}

__global__ void scan_reduce(const int* __restrict__ deg, int* __restrict__ partial, int N) {
    __shared__ int red[256];
    int base = blockIdx.x * 1024;
    int s = 0;
    for (int i = threadIdx.x; i < 1024; i += 256) {
        int idx = base + i;
        s += (idx < N) ? deg[idx] : 0;
    }
    red[threadIdx.x] = s;
    __syncthreads();
    for (int off = 128; off > 0; off >>= 1) {
        if (threadIdx.x < off) red[threadIdx.x] += red[threadIdx.x + off];
        __syncthreads();
    }
    if (threadIdx.x == 0) partial[blockIdx.x] = red[0];
}

__global__ void scan_partials(int* __restrict__ partial, int nb,
                              int* __restrict__ row_start, int N, int E) {
    if (threadIdx.x == 0 && blockIdx.x == 0) {
        int acc = 0;
        for (int i = 0; i < nb; i++) { int v = partial[i]; partial[i] = acc; acc += v; }
        row_start[N] = E;
    }
}

__global__ void scan_chunks(const int* __restrict__ deg, const int* __restrict__ partial,
                            int* __restrict__ row_start, int N) {
    __shared__ int buf[2][1024];
    int t = threadIdx.x;
    int gid = blockIdx.x * 1024 + t;
    int v = (gid < N) ? deg[gid] : 0;
    int cur = 0;
    buf[0][t] = v;
    __syncthreads();
    for (int off = 1; off < 1024; off <<= 1) {
        int nxt = cur ^ 1;
        int val = buf[cur][t];
        if (t >= off) val += buf[cur][t - off];
        buf[nxt][t] = val;
        cur = nxt;
        __syncthreads();
    }
    int incl = buf[cur][t];
    if (gid < N) row_start[gid] = partial[blockIdx.x] + incl - v;  // exclusive
}

__global__ void compute_dinv(const int* __restrict__ deg, float* __restrict__ dinv, int N) {
    int n = blockIdx.x * blockDim.x + threadIdx.x;
    if (n < N) dinv[n] = rsqrtf((float)(deg[n] + 1));  // +1 self loop
}

__global__ void fill_csr(const int* __restrict__ ei, int E,
                         const int* __restrict__ row_start,
                         int* __restrict__ cursor, int* __restrict__ csr_src) {
    int e = blockIdx.x * blockDim.x + threadIdx.x;
    if (e < E) {
        int s = ei[e];
        int d = ei[E + e];
        int pos = atomicAdd(&cursor[d], 1);
        csr_src[row_start[d] + pos] = s;
    }
}

// ---------------- GEMM: C = act(rowscale * (A @ BT^T) + bias) ----------------
// A: [M_pad][K] bf16. BT: [N][K] bf16 (pre-transposed). Block tile 128 x TN,
// 4 waves each 64 x (TN/2). BK=32, global_load_lds width=16 staging.
// TN=256: coalesced LDS-staged epilogue (requires M padded to 128 and bf16 out).
// TN=128: legacy scattered epilogue with row<M guard (fp32-out capable).

template <int TN, bool F32OUT, bool RELU>
__global__ __launch_bounds__(256, 2) void gemm_tile(
    const bf16_t* __restrict__ A, const bf16_t* __restrict__ BT,
    const float* __restrict__ bias, const float* __restrict__ rowscale,
    void* __restrict__ Cv, int M, int N, int K)
{
    constexpr int NT = TN / 32;              // n-subtiles per wave (8 or 4)
    constexpr int STAGE = 128 * 64 + TN * 64; // bytes for sA+sB
    constexpr int SMEM = (TN == 256) ? 32768 : STAGE;
    __shared__ __align__(16) char smem[SMEM];
    bf16_t* sA = (bf16_t*)smem;
    bf16_t* sB = (bf16_t*)(smem + 128 * 64);
    bf16_t* sC = (bf16_t*)smem;

    const int tid  = threadIdx.x;
    const int lane = tid & 63;
    const int wave = tid >> 6;
    const int bn = blockIdx.x * TN;
    const int bm = blockIdx.y * 128;
    const int wm = (wave & 1) * 64;
    const int wn = (wave >> 1) * (TN / 2);
    const int lm = lane & 15;
    const int lq = lane >> 4;

    const int r4 = lane >> 2;          // row within 16-row group
    const int kq = (lane & 3) * 8;     // k offset (elements)

    f32x4 acc[4][NT] = {};

    const int nkb = K >> 5;
    for (int kb = 0; kb < nkb; kb++) {
        const int k0 = kb * 32;
#pragma unroll
        for (int r = 0; r < 2; r++) {               // A: 8 groups of 16 rows
            const int g = r * 4 + wave;
            const int row = g * 16 + r4;
            __builtin_amdgcn_global_load_lds(
                (const AS1 unsigned int*)(A + (size_t)(bm + row) * K + k0 + kq),
                (AS3 unsigned int*)((AS3 char*)(AS3 bf16_t*)sA + g * 1024),
                16, 0, 0);
        }
#pragma unroll
        for (int r = 0; r < TN / 64; r++) {         // B: TN/16 groups of 16 rows
            const int g = r * 4 + wave;
            const int row = g * 16 + r4;
            __builtin_amdgcn_global_load_lds(
                (const AS1 unsigned int*)(BT + (size_t)(bn + row) * K + k0 + kq),
                (AS3 unsigned int*)((AS3 char*)(AS3 bf16_t*)sB + g * 1024),
                16, 0, 0);
        }
        __syncthreads();

        bf16x8 af[4], bfr[NT];
#pragma unroll
        for (int mt = 0; mt < 4; mt++)
            af[mt] = *reinterpret_cast<bf16x8*>(&sA[(wm + mt * 16 + lm) * 32 + lq * 8]);
#pragma unroll
        for (int nt = 0; nt < NT; nt++)
            bfr[nt] = *reinterpret_cast<bf16x8*>(&sB[(wn + nt * 16 + lm) * 32 + lq * 8]);
#pragma unroll
        for (int mt = 0; mt < 4; mt++)
#pragma unroll
            for (int nt = 0; nt < NT; nt++)
                acc[mt][nt] = __builtin_amdgcn_mfma_f32_16x16x32_bf16(af[mt], bfr[nt], acc[mt][nt], 0, 0, 0);
        __syncthreads();
    }

    if (TN == 256) {
        // coalesced epilogue: 2 passes of 64 rows through LDS (32 KB)
        const size_t rowbytes = (size_t)N * 2;
#pragma unroll
        for (int p = 0; p < 2; p++) {
            if (p) __syncthreads();                 // sC reads of pass 0 done
            if ((wave & 1) == p) {
#pragma unroll
                for (int nt = 0; nt < NT; nt++) {
                    const int col = wn + nt * 16 + lm;
                    const float bv = bias ? bias[bn + col] : 0.0f;
#pragma unroll
                    for (int mt = 0; mt < 4; mt++) {
#pragma unroll
                        for (int r = 0; r < 4; r++) {
                            const int lrow = mt * 16 + lq * 4 + r;
                            float v = acc[mt][nt][r] + bv;
                            if (rowscale) v *= rowscale[bm + p * 64 + lrow];
                            if (RELU) v = fmaxf(v, 0.0f);
                            sC[lrow * 256 + col] = (bf16_t)v;
                        }
                    }
                }
            }
            __syncthreads();
            char* outbase = (char*)Cv + (size_t)(bm + p * 64) * rowbytes + (size_t)bn * 2;
#pragma unroll
            for (int j = 0; j < 8; j++) {
                const int idx = j * 4096 + tid * 16;
                const int row = idx >> 9;            // 512 B per LDS row
                const int colb = idx & 511;
                *reinterpret_cast<uint4*>(outbase + (size_t)row * rowbytes + colb) =
                    *reinterpret_cast<const uint4*>((char*)sC + idx);
            }
        }
    } else {
        // legacy epilogue (dnn2): C/D layout col=lane&15, row=lq*4+reg
#pragma unroll
        for (int nt = 0; nt < NT; nt++) {
            const int col = bn + wn + nt * 16 + lm;
            const float bv = bias ? bias[col] : 0.0f;
#pragma unroll
            for (int mt = 0; mt < 4; mt++) {
#pragma unroll
                for (int r = 0; r < 4; r++) {
                    const int row = bm + wm + mt * 16 + lq * 4 + r;
                    if (row < M) {
                        float v = acc[mt][nt][r] + bv;
                        if (rowscale) v *= rowscale[row];
                        if (RELU) v = fmaxf(v, 0.0f);
                        if (F32OUT) ((float*)Cv)[(size_t)row * N + col] = v;
                        else        ((bf16_t*)Cv)[(size_t)row * N + col] = (bf16_t)v;
                    }
                }
            }
        }
    }
}

// ---------------- aggregation ----------------
// hw is pre-scaled: hw[s] = dinv[s] * (h W)[s].
// h_out[n] = dinv[n] * ( hw[n] + sum_{s->n} hw[s] ) + bias
// one wave per node; lane handles 8 contiguous features (512 = 64*8).

__global__ __launch_bounds__(256) void aggregate(
    const bf16_t* __restrict__ hw, const float* __restrict__ dinv,
    const int* __restrict__ row_start, const int* __restrict__ csr_src,
    const float* __restrict__ bias, bf16_t* __restrict__ h_out, int N)
{
    const int n = blockIdx.x * 4 + (threadIdx.x >> 6);
    const int lane = threadIdx.x & 63;
    if (n >= N) return;

    const float dn = dinv[n];
    const int f = lane * 8;

    float acc[8];
    {   // self term (already scaled by dinv[n])
        uint4 u = *reinterpret_cast<const uint4*>(hw + (size_t)n * D_HID + f);
        const unsigned short* hv = reinterpret_cast<const unsigned short*>(&u);
#pragma unroll
        for (int j = 0; j < 8; j++) acc[j] = bf16_bits_to_f32(hv[j]);
    }

    const int beg = row_start[n];
    const int cnt = row_start[n + 1] - beg;

    int i = 0;
    for (; i + 4 <= cnt; i += 4) {
        const int s0 = csr_src[beg + i];
        const int s1 = csr_src[beg + i + 1];
        const int s2 = csr_src[beg + i + 2];
        const int s3 = csr_src[beg + i + 3];
        uint4 u0 = *reinterpret_cast<const uint4*>(hw + (size_t)s0 * D_HID + f);
        uint4 u1 = *reinterpret_cast<const uint4*>(hw + (size_t)s1 * D_HID + f);
        uint4 u2 = *reinterpret_cast<const uint4*>(hw + (size_t)s2 * D_HID + f);
        uint4 u3 = *reinterpret_cast<const uint4*>(hw + (size_t)s3 * D_HID + f);
        const unsigned short* h0 = reinterpret_cast<const unsigned short*>(&u0);
        const unsigned short* h1 = reinterpret_cast<const unsigned short*>(&u1);
        const unsigned short* h2 = reinterpret_cast<const unsigned short*>(&u2);
        const unsigned short* h3 = reinterpret_cast<const unsigned short*>(&u3);
#pragma unroll
        for (int j = 0; j < 8; j++) {
            float t0 = bf16_bits_to_f32(h0[j]) + bf16_bits_to_f32(h1[j]);
            float t1 = bf16_bits_to_f32(h2[j]) + bf16_bits_to_f32(h3[j]);
            acc[j] += t0 + t1;
        }
    }
    if (i < cnt) {
        int s0 = csr_src[beg + i];
        uint4 u0 = *reinterpret_cast<const uint4*>(hw + (size_t)s0 * D_HID + f);
        for (; i < cnt; ) {
            i++;
            uint4 u1;
            if (i < cnt) {
                int s1 = csr_src[beg + i];
                u1 = *reinterpret_cast<const uint4*>(hw + (size_t)s1 * D_HID + f);
            }
            const unsigned short* hv = reinterpret_cast<const unsigned short*>(&u0);
#pragma unroll
            for (int j = 0; j < 8; j++) acc[j] += bf16_bits_to_f32(hv[j]);
            u0 = u1;
        }
    }

    bf16_t outv[8];
#pragma unroll
    for (int j = 0; j < 8; j++) outv[j] = (bf16_t)(fmaf(dn, acc[j], bias[f + j]));
    *reinterpret_cast<uint4*>(h_out + (size_t)n * D_HID + f) = *reinterpret_cast<const uint4*>(outv);
}

// ---------------- orchestration ----------------

extern "C" void kernel_launch(void* const* d_in, const int* in_sizes, int n_in,
                              void* d_out, int out_size, void* d_ws, size_t ws_size,
                              hipStream_t stream) {
    const int N = N_NODES, E = N_EDGES;

    const float* x  = (const float*)d_in[0];
    const int*   ei = (const int*)d_in[1];
    const float* W1 = (const float*)d_in[2];
    const float* b1 = (const float*)d_in[3];
    const float* Wc = (const float*)d_in[4];
    const float* bc = (const float*)d_in[5];
    const float* W2 = (const float*)d_in[6];
    const float* b2 = (const float*)d_in[7];
    float* out = (float*)d_out;

    char* ws = (char*)d_ws;
    size_t off = 0;
    auto alloc = [&](size_t bytes) -> void* {
        void* p = ws + off;
        off += (bytes + 255) & ~(size_t)255;
        return p;
    };
    int*    deg       = (int*)alloc((size_t)N * 4);
    int*    cursor    = (int*)alloc((size_t)N * 4);
    int*    row_start = (int*)alloc((size_t)(N + 1) * 4);
    int*    partial   = (int*)alloc(256 * 4);
    float*  dinv      = (float*)alloc((size_t)N_PAD * 4);  // padded: GEMM epilogue reads rows < N_PAD
    int*    csr_src   = (int*)alloc((size_t)E * 4);
    bf16_t* h         = (bf16_t*)alloc((size_t)N_PAD * D_HID * 2);
    bf16_t* hw        = (bf16_t*)alloc((size_t)N_PAD * D_HID * 2);
    bf16_t* xb        = (bf16_t*)alloc((size_t)N_PAD * D_IN * 2);
    bf16_t* W1t       = (bf16_t*)alloc((size_t)D_HID * D_IN * 2);
    bf16_t* Wct       = (bf16_t*)alloc((size_t)N_LAYERS * D_HID * D_HID * 2);
    bf16_t* W2t       = (bf16_t*)alloc((size_t)D_OUT * D_HID * 2);

    hipMemsetAsync(deg, 0, (size_t)N * 4, stream);
    hipMemsetAsync(cursor, 0, (size_t)N * 4, stream);
    hipMemsetAsync(dinv + N, 0, (size_t)(N_PAD - N) * 4, stream);  // finite pad rowscale

    // conversions: x flat; weights transposed to [N][K]
    {
        int n = N * D_IN;
        f32_to_bf16<<<(n / 4 + 255) / 256, 256, 0, stream>>>(x, xb, n);
        dim3 tb(32, 8);
        transpose_to_bf16<<<dim3(D_HID / 32, D_IN / 32), tb, 0, stream>>>(W1, W1t, D_IN, D_HID);
        for (int i = 0; i < N_LAYERS; i++)
            transpose_to_bf16<<<dim3(D_HID / 32, D_HID / 32), tb, 0, stream>>>(
                Wc + (size_t)i * D_HID * D_HID, Wct + (size_t)i * D_HID * D_HID, D_HID, D_HID);
        transpose_to_bf16<<<dim3(D_OUT / 32, D_HID / 32), tb, 0, stream>>>(W2, W2t, D_HID, D_OUT);
    }

    // CSR build
    count_deg<<<(E + 255) / 256, 256, 0, stream>>>(ei + E, deg, E);
    const int nch = (N + 1023) / 1024;
    scan_reduce<<<nch, 256, 0, stream>>>(deg, partial, N);
    scan_partials<<<1, 64, 0, stream>>>(partial, nch, row_start, N, E);
    scan_chunks<<<nch, 1024, 0, stream>>>(deg, partial, row_start, N);
    compute_dinv<<<(N + 255) / 256, 256, 0, stream>>>(deg, dinv, N);
    fill_csr<<<(E + 255) / 256, 256, 0, stream>>>(ei, E, row_start, cursor, csr_src);

    const dim3 blk(256);
    const int mg = N_PAD / 128;  // 391

    // dnn1: h = relu(x @ W1 + b1)
    gemm_tile<256, false, true><<<dim3(D_HID / 256, mg), blk, 0, stream>>>(
        xb, W1t, b1, nullptr, h, N_PAD, D_HID, D_IN);

    // GCN layers: hw = dinv .* (h @ Wc[i]); h = dinv .* (hw[self] + gather-sum) + bc[i]
    for (int i = 0; i < N_LAYERS; i++) {
        gemm_tile<256, false, false><<<dim3(D_HID / 256, mg), blk, 0, stream>>>(
            h, Wct + (size_t)i * D_HID * D_HID, nullptr, dinv, hw, N_PAD, D_HID, D_HID);
        aggregate<<<(N + 3) / 4, 256, 0, stream>>>(hw, dinv, row_start, csr_src,
                                                   bc + (size_t)i * D_HID, h, N);
    }

    // dnn2: out = h @ W2 + b2 (fp32 out, 128-wide tile)
    gemm_tile<128, true, false><<<dim3(D_OUT / 128, mg), blk, 0, stream>>>(
        h, W2t, b2, nullptr, out, N, D_OUT, D_HID);
}

// Round 6
// 818.211 us; speedup vs baseline: 1.0981x; 1.0431x over previous
//
#include <hip/hip_runtime.h>

typedef __bf16 bf16_t;
typedef __bf16 bf16x8 __attribute__((ext_vector_type(8)));
typedef float f32x4 __attribute__((ext_vector_type(4)));

#define N_NODES 50000
#define N_PAD   50048   // padded to multiple of 128 for 128-row GEMM tiles
#define N_EDGES 400000
#define D_IN    256
#define D_HID   512
#define D_OUT   128
#define N_LAYERS 4

#define AS1 __attribute__((address_space(1)))
#define AS3 __attribute__((address_space(3)))

static __device__ __forceinline__ float bf16_bits_to_f32(unsigned short u) {
    return __uint_as_float(((unsigned int)u) << 16);
}

// ---------------- fp32 -> bf16 conversion (flat, for x) ----------------

__global__ void f32_to_bf16(const float* __restrict__ in, bf16_t* __restrict__ out, int n) {
    int idx = (blockIdx.x * blockDim.x + threadIdx.x) * 4;
    if (idx + 3 < n) {
        float4 v = *reinterpret_cast<const float4*>(in + idx);
        bf16_t o[4] = {(bf16_t)v.x, (bf16_t)v.y, (bf16_t)v.z, (bf16_t)v.w};
        *reinterpret_cast<uint2*>(out + idx) = *reinterpret_cast<const uint2*>(o);
    } else {
        for (int j = idx; j < n; j++) out[j] = (bf16_t)in[j];
    }
}

// ---------------- fp32 [R][C] -> bf16 transposed [C][R] (for weights) ----------------

__global__ void transpose_to_bf16(const float* __restrict__ in, bf16_t* __restrict__ out,
                                  int R, int C) {
    __shared__ float tile[32][33];
    const int c0 = blockIdx.x * 32;
    const int r0 = blockIdx.y * 32;
    for (int i = threadIdx.y; i < 32; i += 8)
        tile[i][threadIdx.x] = in[(size_t)(r0 + i) * C + c0 + threadIdx.x];
    __syncthreads();
    for (int i = threadIdx.y; i < 32; i += 8)
        out[(size_t)(c0 + i) * R + r0 + threadIdx.x] = (bf16_t)tile[threadIdx.x][i];
}

// ---------------- degree / CSR build ----------------

__global__ void count_deg(const int* __restrict__ dst, int* __restrict__ deg, int E) {
    int e = blockIdx.x * blockDim.x + threadIdx.x;
    if (e < E) atomicAdd(&deg[dst[e]], 1);
}

__global__ void scan_reduce(const int* __restrict__ deg, int* __restrict__ partial, int N) {
    __shared__ int red[256];
    int base = blockIdx.x * 1024;
    int s = 0;
    for (int i = threadIdx.x; i < 1024; i += 256) {
        int idx = base + i;
        s += (idx < N) ? deg[idx] : 0;
    }
    red[threadIdx.x] = s;
    __syncthreads();
    for (int off = 128; off > 0; off >>= 1) {
        if (threadIdx.x < off) red[threadIdx.x] += red[threadIdx.x + off];
        __syncthreads();
    }
    if (threadIdx.x == 0) partial[blockIdx.x] = red[0];
}

__global__ void scan_partials(int* __restrict__ partial, int nb,
                              int* __restrict__ row_start, int N, int E) {
    if (threadIdx.x == 0 && blockIdx.x == 0) {
        int acc = 0;
        for (int i = 0; i < nb; i++) { int v = partial[i]; partial[i] = acc; acc += v; }
        row_start[N] = E;
    }
}

__global__ void scan_chunks(const int* __restrict__ deg, const int* __restrict__ partial,
                            int* __restrict__ row_start, int N) {
    __shared__ int buf[2][1024];
    int t = threadIdx.x;
    int gid = blockIdx.x * 1024 + t;
    int v = (gid < N) ? deg[gid] : 0;
    int cur = 0;
    buf[0][t] = v;
    __syncthreads();
    for (int off = 1; off < 1024; off <<= 1) {
        int nxt = cur ^ 1;
        int val = buf[cur][t];
        if (t >= off) val += buf[cur][t - off];
        buf[nxt][t] = val;
        cur = nxt;
        __syncthreads();
    }
    int incl = buf[cur][t];
    if (gid < N) row_start[gid] = partial[blockIdx.x] + incl - v;  // exclusive
}

__global__ void compute_dinv(const int* __restrict__ deg, float* __restrict__ dinv, int N) {
    int n = blockIdx.x * blockDim.x + threadIdx.x;
    if (n < N) dinv[n] = rsqrtf((float)(deg[n] + 1));  // +1 self loop
}

__global__ void fill_csr(const int* __restrict__ ei, int E,
                         const int* __restrict__ row_start,
                         int* __restrict__ cursor, int* __restrict__ csr_src) {
    int e = blockIdx.x * blockDim.x + threadIdx.x;
    if (e < E) {
        int s = ei[e];
        int d = ei[E + e];
        int pos = atomicAdd(&cursor[d], 1);
        csr_src[row_start[d] + pos] = s;
    }
}

// ---------------- GEMM: C = act(rowscale * (A @ BT^T) + bias) ----------------
// A: [M_pad][K] bf16. BT: [N][K] bf16 (pre-transposed). Block tile 128 x TN,
// 4 waves each 64 x (TN/2). BK=64, global_load_lds width=16 staging.
// LDS layout XOR-swizzled: row slab = 64 elems (8 chunks of 16B); chunk c of row r
// holds k-group (c ^ (r&7)) -> 2-way max bank aliasing on fragment reads (free).
// TN=256: coalesced LDS-staged epilogue. TN=128: scattered epilogue (fp32-out capable).

template <int TN, bool F32OUT, bool RELU>
__global__ __launch_bounds__(256, 2) void gemm_tile(
    const bf16_t* __restrict__ A, const bf16_t* __restrict__ BT,
    const float* __restrict__ bias, const float* __restrict__ rowscale,
    void* __restrict__ Cv, int M, int N, int K)
{
    constexpr int NT = TN / 32;                 // n-subtiles per wave (8 or 4)
    constexpr int SMEM = 128 * 128 + TN * 128;  // bytes: sA + sB (48 KB / 32 KB)
    __shared__ __align__(16) char smem[SMEM];
    bf16_t* sA = (bf16_t*)smem;
    bf16_t* sB = (bf16_t*)(smem + 128 * 128);
    bf16_t* sC = (bf16_t*)smem;                 // epilogue reuse (TN=256: 64x264 = 33.8 KB)

    const int tid  = threadIdx.x;
    const int lane = tid & 63;
    const int wave = tid >> 6;
    const int bn = blockIdx.x * TN;
    const int bm = blockIdx.y * 128;
    const int wm = (wave & 1) * 64;
    const int wn = (wave >> 1) * (TN / 2);
    const int lm = lane & 15;
    const int lq = lane >> 4;

    // staging: each 1KB wave-load covers 8 rows x 8 chunks; lane (r8,c8)
    const int r8 = lane >> 3;
    const int c8 = lane & 7;
    const int ksw = (c8 ^ r8) * 8;              // swizzled k-offset (elements)

    f32x4 acc[4][NT] = {};

    const int nkb = K >> 6;
    for (int kb = 0; kb < nkb; kb++) {
        const int k0 = kb * 64;
#pragma unroll
        for (int r = 0; r < 4; r++) {               // A: 16 groups of 8 rows
            const int g = r * 4 + wave;
            __builtin_amdgcn_global_load_lds(
                (const AS1 unsigned int*)(A + (size_t)(bm + g * 8 + r8) * K + k0 + ksw),
                (AS3 unsigned int*)((AS3 char*)(AS3 bf16_t*)sA + g * 1024),
                16, 0, 0);
        }
#pragma unroll
        for (int r = 0; r < TN / 32; r++) {         // B: TN/8 groups of 8 rows
            const int g = r * 4 + wave;
            __builtin_amdgcn_global_load_lds(
                (const AS1 unsigned int*)(BT + (size_t)(bn + g * 8 + r8) * K + k0 + ksw),
                (AS3 unsigned int*)((AS3 char*)(AS3 bf16_t*)sB + g * 1024),
                16, 0, 0);
        }
        __syncthreads();

#pragma unroll
        for (int s = 0; s < 2; s++) {               // two K=32 steps per BK=64
            bf16x8 af[4], bfr[NT];
#pragma unroll
            for (int mt = 0; mt < 4; mt++) {
                const int R = wm + mt * 16 + lm;
                const int g = s * 4 + lq;
                af[mt] = *reinterpret_cast<bf16x8*>(&sA[R * 64 + ((g ^ (R & 7)) * 8)]);
            }
#pragma unroll
            for (int nt = 0; nt < NT; nt++) {
                const int R = wn + nt * 16 + lm;
                const int g = s * 4 + lq;
                bfr[nt] = *reinterpret_cast<bf16x8*>(&sB[R * 64 + ((g ^ (R & 7)) * 8)]);
            }
#pragma unroll
            for (int mt = 0; mt < 4; mt++)
#pragma unroll
                for (int nt = 0; nt < NT; nt++)
                    acc[mt][nt] = __builtin_amdgcn_mfma_f32_16x16x32_bf16(af[mt], bfr[nt], acc[mt][nt], 0, 0, 0);
        }
        __syncthreads();
    }

    if (TN == 256) {
        // coalesced epilogue: 2 passes of 64 rows through LDS; sC row stride 264 elems
        const size_t rowbytes = (size_t)N * 2;
#pragma unroll
        for (int p = 0; p < 2; p++) {
            if (p) __syncthreads();
            if ((wave & 1) == p) {
#pragma unroll
                for (int nt = 0; nt < NT; nt++) {
                    const int col = wn + nt * 16 + lm;
                    const float bv = bias ? bias[bn + col] : 0.0f;
#pragma unroll
                    for (int mt = 0; mt < 4; mt++) {
#pragma unroll
                        for (int r = 0; r < 4; r++) {
                            const int lrow = mt * 16 + lq * 4 + r;
                            float v = acc[mt][nt][r] + bv;
                            if (rowscale) v *= rowscale[bm + p * 64 + lrow];
                            if (RELU) v = fmaxf(v, 0.0f);
                            sC[lrow * 264 + col] = (bf16_t)v;
                        }
                    }
                }
            }
            __syncthreads();
            char* outbase = (char*)Cv + (size_t)(bm + p * 64) * rowbytes + (size_t)bn * 2;
#pragma unroll
            for (int j = 0; j < 8; j++) {
                const int idx = j * 4096 + tid * 16;
                const int row = idx >> 9;            // 512 data bytes per row
                const int colb = idx & 511;
                *reinterpret_cast<uint4*>(outbase + (size_t)row * rowbytes + colb) =
                    *reinterpret_cast<const uint4*>((char*)sC + (size_t)row * 528 + colb);
            }
        }
    } else {
        // scattered epilogue (dnn2): C/D layout col=lane&15, row=lq*4+reg
#pragma unroll
        for (int nt = 0; nt < NT; nt++) {
            const int col = bn + wn + nt * 16 + lm;
            const float bv = bias ? bias[col] : 0.0f;
#pragma unroll
            for (int mt = 0; mt < 4; mt++) {
#pragma unroll
                for (int r = 0; r < 4; r++) {
                    const int row = bm + wm + mt * 16 + lq * 4 + r;
                    if (row < M) {
                        float v = acc[mt][nt][r] + bv;
                        if (rowscale) v *= rowscale[row];
                        if (RELU) v = fmaxf(v, 0.0f);
                        if (F32OUT) ((float*)Cv)[(size_t)row * N + col] = v;
                        else        ((bf16_t*)Cv)[(size_t)row * N + col] = (bf16_t)v;
                    }
                }
            }
        }
    }
}

// ---------------- aggregation ----------------
// hw is pre-scaled: hw[s] = dinv[s] * (h W)[s].
// h_out[n] = dinv[n] * ( hw[n] + sum_{s->n} hw[s] ) + bias
// one wave per node; lane handles 8 contiguous features (512 = 64*8).

__global__ __launch_bounds__(256) void aggregate(
    const bf16_t* __restrict__ hw, const float* __restrict__ dinv,
    const int* __restrict__ row_start, const int* __restrict__ csr_src,
    const float* __restrict__ bias, bf16_t* __restrict__ h_out, int N)
{
    const int n = blockIdx.x * 4 + (threadIdx.x >> 6);
    const int lane = threadIdx.x & 63;
    if (n >= N) return;

    const float dn = dinv[n];
    const int f = lane * 8;

    float acc[8];
    {   // self term (already scaled by dinv[n])
        uint4 u = *reinterpret_cast<const uint4*>(hw + (size_t)n * D_HID + f);
        const unsigned short* hv = reinterpret_cast<const unsigned short*>(&u);
#pragma unroll
        for (int j = 0; j < 8; j++) acc[j] = bf16_bits_to_f32(hv[j]);
    }

    const int beg = row_start[n];
    const int cnt = row_start[n + 1] - beg;

    int i = 0;
    for (; i + 4 <= cnt; i += 4) {
        const int s0 = csr_src[beg + i];
        const int s1 = csr_src[beg + i + 1];
        const int s2 = csr_src[beg + i + 2];
        const int s3 = csr_src[beg + i + 3];
        uint4 u0 = *reinterpret_cast<const uint4*>(hw + (size_t)s0 * D_HID + f);
        uint4 u1 = *reinterpret_cast<const uint4*>(hw + (size_t)s1 * D_HID + f);
        uint4 u2 = *reinterpret_cast<const uint4*>(hw + (size_t)s2 * D_HID + f);
        uint4 u3 = *reinterpret_cast<const uint4*>(hw + (size_t)s3 * D_HID + f);
        const unsigned short* h0 = reinterpret_cast<const unsigned short*>(&u0);
        const unsigned short* h1 = reinterpret_cast<const unsigned short*>(&u1);
        const unsigned short* h2 = reinterpret_cast<const unsigned short*>(&u2);
        const unsigned short* h3 = reinterpret_cast<const unsigned short*>(&u3);
#pragma unroll
        for (int j = 0; j < 8; j++) {
            float t0 = bf16_bits_to_f32(h0[j]) + bf16_bits_to_f32(h1[j]);
            float t1 = bf16_bits_to_f32(h2[j]) + bf16_bits_to_f32(h3[j]);
            acc[j] += t0 + t1;
        }
    }
    if (i < cnt) {
        int s0 = csr_src[beg + i];
        uint4 u0 = *reinterpret_cast<const uint4*>(hw + (size_t)s0 * D_HID + f);
        for (; i < cnt; ) {
            i++;
            uint4 u1;
            if (i < cnt) {
                int s1 = csr_src[beg + i];
                u1 = *reinterpret_cast<const uint4*>(hw + (size_t)s1 * D_HID + f);
            }
            const unsigned short* hv = reinterpret_cast<const unsigned short*>(&u0);
#pragma unroll
            for (int j = 0; j < 8; j++) acc[j] += bf16_bits_to_f32(hv[j]);
            u0 = u1;
        }
    }

    bf16_t outv[8];
#pragma unroll
    for (int j = 0; j < 8; j++) outv[j] = (bf16_t)(fmaf(dn, acc[j], bias[f + j]));
    *reinterpret_cast<uint4*>(h_out + (size_t)n * D_HID + f) = *reinterpret_cast<const uint4*>(outv);
}

// ---------------- orchestration ----------------

extern "C" void kernel_launch(void* const* d_in, const int* in_sizes, int n_in,
                              void* d_out, int out_size, void* d_ws, size_t ws_size,
                              hipStream_t stream) {
    const int N = N_NODES, E = N_EDGES;

    const float* x  = (const float*)d_in[0];
    const int*   ei = (const int*)d_in[1];
    const float* W1 = (const float*)d_in[2];
    const float* b1 = (const float*)d_in[3];
    const float* Wc = (const float*)d_in[4];
    const float* bc = (const float*)d_in[5];
    const float* W2 = (const float*)d_in[6];
    const float* b2 = (const float*)d_in[7];
    float* out = (float*)d_out;

    char* ws = (char*)d_ws;
    size_t off = 0;
    auto alloc = [&](size_t bytes) -> void* {
        void* p = ws + off;
        off += (bytes + 255) & ~(size_t)255;
        return p;
    };
    int*    deg       = (int*)alloc((size_t)N * 4);
    int*    cursor    = (int*)alloc((size_t)N * 4);
    int*    row_start = (int*)alloc((size_t)(N + 1) * 4);
    int*    partial   = (int*)alloc(256 * 4);
    float*  dinv      = (float*)alloc((size_t)N_PAD * 4);  // padded: epilogue reads rows < N_PAD
    int*    csr_src   = (int*)alloc((size_t)E * 4);
    bf16_t* h         = (bf16_t*)alloc((size_t)N_PAD * D_HID * 2);
    bf16_t* hw        = (bf16_t*)alloc((size_t)N_PAD * D_HID * 2);
    bf16_t* xb        = (bf16_t*)alloc((size_t)N_PAD * D_IN * 2);
    bf16_t* W1t       = (bf16_t*)alloc((size_t)D_HID * D_IN * 2);
    bf16_t* Wct       = (bf16_t*)alloc((size_t)N_LAYERS * D_HID * D_HID * 2);
    bf16_t* W2t       = (bf16_t*)alloc((size_t)D_OUT * D_HID * 2);

    hipMemsetAsync(deg, 0, (size_t)N * 4, stream);
    hipMemsetAsync(cursor, 0, (size_t)N * 4, stream);
    hipMemsetAsync(dinv + N, 0, (size_t)(N_PAD - N) * 4, stream);  // finite pad rowscale

    // conversions: x flat; weights transposed to [N][K]
    {
        int n = N * D_IN;
        f32_to_bf16<<<(n / 4 + 255) / 256, 256, 0, stream>>>(x, xb, n);
        dim3 tb(32, 8);
        transpose_to_bf16<<<dim3(D_HID / 32, D_IN / 32), tb, 0, stream>>>(W1, W1t, D_IN, D_HID);
        for (int i = 0; i < N_LAYERS; i++)
            transpose_to_bf16<<<dim3(D_HID / 32, D_HID / 32), tb, 0, stream>>>(
                Wc + (size_t)i * D_HID * D_HID, Wct + (size_t)i * D_HID * D_HID, D_HID, D_HID);
        transpose_to_bf16<<<dim3(D_OUT / 32, D_HID / 32), tb, 0, stream>>>(W2, W2t, D_HID, D_OUT);
    }

    // CSR build
    count_deg<<<(E + 255) / 256, 256, 0, stream>>>(ei + E, deg, E);
    const int nch = (N + 1023) / 1024;
    scan_reduce<<<nch, 256, 0, stream>>>(deg, partial, N);
    scan_partials<<<1, 64, 0, stream>>>(partial, nch, row_start, N, E);
    scan_chunks<<<nch, 1024, 0, stream>>>(deg, partial, row_start, N);
    compute_dinv<<<(N + 255) / 256, 256, 0, stream>>>(deg, dinv, N);
    fill_csr<<<(E + 255) / 256, 256, 0, stream>>>(ei, E, row_start, cursor, csr_src);

    const dim3 blk(256);
    const int mg = N_PAD / 128;  // 391

    // dnn1: h = relu(x @ W1 + b1)
    gemm_tile<256, false, true><<<dim3(D_HID / 256, mg), blk, 0, stream>>>(
        xb, W1t, b1, nullptr, h, N_PAD, D_HID, D_IN);

    // GCN layers: hw = dinv .* (h @ Wc[i]); h = dinv .* (hw[self] + gather-sum) + bc[i]
    for (int i = 0; i < N_LAYERS; i++) {
        gemm_tile<256, false, false><<<dim3(D_HID / 256, mg), blk, 0, stream>>>(
            h, Wct + (size_t)i * D_HID * D_HID, nullptr, dinv, hw, N_PAD, D_HID, D_HID);
        aggregate<<<(N + 3) / 4, 256, 0, stream>>>(hw, dinv, row_start, csr_src,
                                                   bc + (size_t)i * D_HID, h, N);
    }

    // dnn2: out = h @ W2 + b2 (fp32 out, 128-wide tile)
    gemm_tile<128, true, false><<<dim3(D_OUT / 128, mg), blk, 0, stream>>>(
        h, W2t, b2, nullptr, out, N, D_OUT, D_HID);
}

// Round 7
// 756.893 us; speedup vs baseline: 1.1871x; 1.0810x over previous
//
#include <hip/hip_runtime.h>

typedef __bf16 bf16_t;
typedef __bf16 bf16x8 __attribute__((ext_vector_type(8)));
typedef float f32x4 __attribute__((ext_vector_type(4)));

#define N_NODES 50000
#define N_PAD   50048   // padded to multiple of 128 for 128-row GEMM tiles
#define N_EDGES 400000
#define D_IN    256
#define D_HID   512
#define D_OUT   128
#define N_LAYERS 4

#define AS1 __attribute__((address_space(1)))
#define AS3 __attribute__((address_space(3)))

static __device__ __forceinline__ float bf16_bits_to_f32(unsigned short u) {
    return __uint_as_float(((unsigned int)u) << 16);
}

// ---------------- fp32 -> bf16 conversion (flat, for x) ----------------

__global__ void f32_to_bf16(const float* __restrict__ in, bf16_t* __restrict__ out, int n) {
    int idx = (blockIdx.x * blockDim.x + threadIdx.x) * 4;
    if (idx + 3 < n) {
        float4 v = *reinterpret_cast<const float4*>(in + idx);
        bf16_t o[4] = {(bf16_t)v.x, (bf16_t)v.y, (bf16_t)v.z, (bf16_t)v.w};
        *reinterpret_cast<uint2*>(out + idx) = *reinterpret_cast<const uint2*>(o);
    } else {
        for (int j = idx; j < n; j++) out[j] = (bf16_t)in[j];
    }
}

// ---------------- fp32 [R][C] -> bf16 transposed [C][R] (for weights) ----------------

__global__ void transpose_to_bf16(const float* __restrict__ in, bf16_t* __restrict__ out,
                                  int R, int C) {
    __shared__ float tile[32][33];
    const int c0 = blockIdx.x * 32;
    const int r0 = blockIdx.y * 32;
    for (int i = threadIdx.y; i < 32; i += 8)
        tile[i][threadIdx.x] = in[(size_t)(r0 + i) * C + c0 + threadIdx.x];
    __syncthreads();
    for (int i = threadIdx.y; i < 32; i += 8)
        out[(size_t)(c0 + i) * R + r0 + threadIdx.x] = (bf16_t)tile[threadIdx.x][i];
}

// ---------------- degree / CSR build ----------------

__global__ void count_deg(const int* __restrict__ dst, int* __restrict__ deg, int E) {
    int e = blockIdx.x * blockDim.x + threadIdx.x;
    if (e < E) atomicAdd(&deg[dst[e]], 1);
}

__global__ void scan_reduce(const int* __restrict__ deg, int* __restrict__ partial, int N) {
    __shared__ int red[256];
    int base = blockIdx.x * 1024;
    int s = 0;
    for (int i = threadIdx.x; i < 1024; i += 256) {
        int idx = base + i;
        s += (idx < N) ? deg[idx] : 0;
    }
    red[threadIdx.x] = s;
    __syncthreads();
    for (int off = 128; off > 0; off >>= 1) {
        if (threadIdx.x < off) red[threadIdx.x] += red[threadIdx.x + off];
        __syncthreads();
    }
    if (threadIdx.x == 0) partial[blockIdx.x] = red[0];
}

__global__ void scan_partials(int* __restrict__ partial, int nb,
                              int* __restrict__ row_start, int N, int E) {
    if (threadIdx.x == 0 && blockIdx.x == 0) {
        int acc = 0;
        for (int i = 0; i < nb; i++) { int v = partial[i]; partial[i] = acc; acc += v; }
        row_start[N] = E;
    }
}

__global__ void scan_chunks(const int* __restrict__ deg, const int* __restrict__ partial,
                            int* __restrict__ row_start, int N) {
    __shared__ int buf[2][1024];
    int t = threadIdx.x;
    int gid = blockIdx.x * 1024 + t;
    int v = (gid < N) ? deg[gid] : 0;
    int cur = 0;
    buf[0][t] = v;
    __syncthreads();
    for (int off = 1; off < 1024; off <<= 1) {
        int nxt = cur ^ 1;
        int val = buf[cur][t];
        if (t >= off) val += buf[cur][t - off];
        buf[nxt][t] = val;
        cur = nxt;
        __syncthreads();
    }
    int incl = buf[cur][t];
    if (gid < N) row_start[gid] = partial[blockIdx.x] + incl - v;  // exclusive
}

__global__ void compute_dinv(const int* __restrict__ deg, float* __restrict__ dinv, int N) {
    int n = blockIdx.x * blockDim.x + threadIdx.x;
    if (n < N) dinv[n] = rsqrtf((float)(deg[n] + 1));  // +1 self loop
}

__global__ void fill_csr(const int* __restrict__ ei, int E,
                         const int* __restrict__ row_start,
                         int* __restrict__ cursor, int* __restrict__ csr_src) {
    int e = blockIdx.x * blockDim.x + threadIdx.x;
    if (e < E) {
        int s = ei[e];
        int d = ei[E + e];
        int pos = atomicAdd(&cursor[d], 1);
        csr_src[row_start[d] + pos] = s;
    }
}

// ---------------- GEMM: C = act(rowscale * (A @ BT^T) + bias) ----------------
// A: [M_pad][K] bf16. BT: [N][K] bf16 (pre-transposed). Block tile 128 x 128,
// 4 waves each 64x64 (acc 64 f32 -> AGPR), BK=64, global_load_lds width=16.
// LDS XOR-swizzled (chunk c of row r holds k-group c^(r&7)): conflict-free reads.
// launch_bounds(256,4): ~128 total regs/wave -> 4 blocks/CU (50% occupancy).
// F32OUT=false: coalesced LDS-staged epilogue. F32OUT=true: scattered (dnn2).

template <bool F32OUT, bool RELU>
__global__ __launch_bounds__(256, 4) void gemm_tile(
    const bf16_t* __restrict__ A, const bf16_t* __restrict__ BT,
    const float* __restrict__ bias, const float* __restrict__ rowscale,
    void* __restrict__ Cv, int M, int N, int K)
{
    __shared__ __align__(16) char smem[32768];  // sA 16KB + sB 16KB; epilogue reuse
    bf16_t* sA = (bf16_t*)smem;
    bf16_t* sB = (bf16_t*)(smem + 128 * 128);
    bf16_t* sC = (bf16_t*)smem;                 // 64 x 136 bf16 = 17.4 KB

    const int tid  = threadIdx.x;
    const int lane = tid & 63;
    const int wave = tid >> 6;
    const int bn = blockIdx.x * 128;
    const int bm = blockIdx.y * 128;
    const int wm = (wave & 1) * 64;
    const int wn = (wave >> 1) * 64;
    const int lm = lane & 15;
    const int lq = lane >> 4;

    // staging: each 1KB wave-load covers 8 rows x 8 chunks; lane (r8,c8)
    const int r8 = lane >> 3;
    const int c8 = lane & 7;
    const int ksw = (c8 ^ r8) * 8;              // swizzled k-offset (elements)

    f32x4 acc[4][4] = {};

    const int nkb = K >> 6;
    for (int kb = 0; kb < nkb; kb++) {
        const int k0 = kb * 64;
#pragma unroll
        for (int r = 0; r < 4; r++) {               // A: 16 groups of 8 rows
            const int g = r * 4 + wave;
            __builtin_amdgcn_global_load_lds(
                (const AS1 unsigned int*)(A + (size_t)(bm + g * 8 + r8) * K + k0 + ksw),
                (AS3 unsigned int*)((AS3 char*)(AS3 bf16_t*)sA + g * 1024),
                16, 0, 0);
        }
#pragma unroll
        for (int r = 0; r < 4; r++) {               // B: 16 groups of 8 rows
            const int g = r * 4 + wave;
            __builtin_amdgcn_global_load_lds(
                (const AS1 unsigned int*)(BT + (size_t)(bn + g * 8 + r8) * K + k0 + ksw),
                (AS3 unsigned int*)((AS3 char*)(AS3 bf16_t*)sB + g * 1024),
                16, 0, 0);
        }
        __syncthreads();

#pragma unroll
        for (int s = 0; s < 2; s++) {               // two K=32 steps per BK=64
            bf16x8 af[4], bfr[4];
#pragma unroll
            for (int mt = 0; mt < 4; mt++) {
                const int R = wm + mt * 16 + lm;
                const int g = s * 4 + lq;
                af[mt] = *reinterpret_cast<bf16x8*>(&sA[R * 64 + ((g ^ (R & 7)) * 8)]);
            }
#pragma unroll
            for (int nt = 0; nt < 4; nt++) {
                const int R = wn + nt * 16 + lm;
                const int g = s * 4 + lq;
                bfr[nt] = *reinterpret_cast<bf16x8*>(&sB[R * 64 + ((g ^ (R & 7)) * 8)]);
            }
#pragma unroll
            for (int mt = 0; mt < 4; mt++)
#pragma unroll
                for (int nt = 0; nt < 4; nt++)
                    acc[mt][nt] = __builtin_amdgcn_mfma_f32_16x16x32_bf16(af[mt], bfr[nt], acc[mt][nt], 0, 0, 0);
        }
        __syncthreads();
    }

    if (!F32OUT) {
        // coalesced epilogue: 2 passes of 64 rows through LDS; sC row stride 136 elems
        const size_t rowbytes = (size_t)N * 2;
#pragma unroll
        for (int p = 0; p < 2; p++) {
            if (p) __syncthreads();
            if ((wave & 1) == p) {
#pragma unroll
                for (int nt = 0; nt < 4; nt++) {
                    const int col = wn + nt * 16 + lm;
                    const float bv = bias ? bias[bn + col] : 0.0f;
#pragma unroll
                    for (int mt = 0; mt < 4; mt++) {
#pragma unroll
                        for (int r = 0; r < 4; r++) {
                            const int lrow = mt * 16 + lq * 4 + r;
                            float v = acc[mt][nt][r] + bv;
                            if (rowscale) v *= rowscale[bm + p * 64 + lrow];
                            if (RELU) v = fmaxf(v, 0.0f);
                            sC[lrow * 136 + col] = (bf16_t)v;
                        }
                    }
                }
            }
            __syncthreads();
            char* outbase = (char*)Cv + (size_t)(bm + p * 64) * rowbytes + (size_t)bn * 2;
#pragma unroll
            for (int j = 0; j < 4; j++) {
                const int idx = j * 4096 + tid * 16;
                const int row = idx >> 8;            // 256 data bytes per row
                const int colb = idx & 255;
                *reinterpret_cast<uint4*>(outbase + (size_t)row * rowbytes + colb) =
                    *reinterpret_cast<const uint4*>((char*)sC + (size_t)row * 272 + colb);
            }
        }
    } else {
        // scattered epilogue (dnn2, fp32 out): C/D layout col=lane&15, row=lq*4+reg
#pragma unroll
        for (int nt = 0; nt < 4; nt++) {
            const int col = bn + wn + nt * 16 + lm;
            const float bv = bias ? bias[col] : 0.0f;
#pragma unroll
            for (int mt = 0; mt < 4; mt++) {
#pragma unroll
                for (int r = 0; r < 4; r++) {
                    const int row = bm + wm + mt * 16 + lq * 4 + r;
                    if (row < M) {
                        float v = acc[mt][nt][r] + bv;
                        if (rowscale) v *= rowscale[row];
                        if (RELU) v = fmaxf(v, 0.0f);
                        ((float*)Cv)[(size_t)row * N + col] = v;
                    }
                }
            }
        }
    }
}

// ---------------- aggregation ----------------
// hw is pre-scaled: hw[s] = dinv[s] * (h W)[s].
// h_out[n] = dinv[n] * ( hw[n] + sum_{s->n} hw[s] ) + bias
// one wave per node; lane handles 8 contiguous features (512 = 64*8).
// Edge loop chunked by 8: 8 independent 16B gathers in flight per wait.

__global__ __launch_bounds__(256) void aggregate(
    const bf16_t* __restrict__ hw, const float* __restrict__ dinv,
    const int* __restrict__ row_start, const int* __restrict__ csr_src,
    const float* __restrict__ bias, bf16_t* __restrict__ h_out, int N)
{
    const int n = blockIdx.x * 4 + (threadIdx.x >> 6);
    const int lane = threadIdx.x & 63;
    if (n >= N) return;

    const float dn = dinv[n];
    const int f = lane * 8;

    float acc[8];
    {   // self term (already scaled by dinv[n])
        uint4 u = *reinterpret_cast<const uint4*>(hw + (size_t)n * D_HID + f);
        const unsigned short* hv = reinterpret_cast<const unsigned short*>(&u);
#pragma unroll
        for (int j = 0; j < 8; j++) acc[j] = bf16_bits_to_f32(hv[j]);
    }

    const int beg = row_start[n];
    const int cnt = row_start[n + 1] - beg;

    int i = 0;
    for (; i + 8 <= cnt; i += 8) {
        uint4 u[8];
#pragma unroll
        for (int q = 0; q < 8; q++) {
            const int s = csr_src[beg + i + q];
            u[q] = *reinterpret_cast<const uint4*>(hw + (size_t)s * D_HID + f);
        }
#pragma unroll
        for (int q = 0; q < 8; q++) {
            const unsigned short* hv = reinterpret_cast<const unsigned short*>(&u[q]);
#pragma unroll
            for (int j = 0; j < 8; j++) acc[j] += bf16_bits_to_f32(hv[j]);
        }
    }
    for (; i + 4 <= cnt; i += 4) {
        uint4 u[4];
#pragma unroll
        for (int q = 0; q < 4; q++) {
            const int s = csr_src[beg + i + q];
            u[q] = *reinterpret_cast<const uint4*>(hw + (size_t)s * D_HID + f);
        }
#pragma unroll
        for (int q = 0; q < 4; q++) {
            const unsigned short* hv = reinterpret_cast<const unsigned short*>(&u[q]);
#pragma unroll
            for (int j = 0; j < 8; j++) acc[j] += bf16_bits_to_f32(hv[j]);
        }
    }
    if (i < cnt) {
        int s0 = csr_src[beg + i];
        uint4 u0 = *reinterpret_cast<const uint4*>(hw + (size_t)s0 * D_HID + f);
        for (; i < cnt; ) {
            i++;
            uint4 u1;
            if (i < cnt) {
                int s1 = csr_src[beg + i];
                u1 = *reinterpret_cast<const uint4*>(hw + (size_t)s1 * D_HID + f);
            }
            const unsigned short* hv = reinterpret_cast<const unsigned short*>(&u0);
#pragma unroll
            for (int j = 0; j < 8; j++) acc[j] += bf16_bits_to_f32(hv[j]);
            u0 = u1;
        }
    }

    bf16_t outv[8];
#pragma unroll
    for (int j = 0; j < 8; j++) outv[j] = (bf16_t)(fmaf(dn, acc[j], bias[f + j]));
    *reinterpret_cast<uint4*>(h_out + (size_t)n * D_HID + f) = *reinterpret_cast<const uint4*>(outv);
}

// ---------------- orchestration ----------------

extern "C" void kernel_launch(void* const* d_in, const int* in_sizes, int n_in,
                              void* d_out, int out_size, void* d_ws, size_t ws_size,
                              hipStream_t stream) {
    const int N = N_NODES, E = N_EDGES;

    const float* x  = (const float*)d_in[0];
    const int*   ei = (const int*)d_in[1];
    const float* W1 = (const float*)d_in[2];
    const float* b1 = (const float*)d_in[3];
    const float* Wc = (const float*)d_in[4];
    const float* bc = (const float*)d_in[5];
    const float* W2 = (const float*)d_in[6];
    const float* b2 = (const float*)d_in[7];
    float* out = (float*)d_out;

    char* ws = (char*)d_ws;
    size_t off = 0;
    auto alloc = [&](size_t bytes) -> void* {
        void* p = ws + off;
        off += (bytes + 255) & ~(size_t)255;
        return p;
    };
    int*    deg       = (int*)alloc((size_t)N * 4);
    int*    cursor    = (int*)alloc((size_t)N * 4);
    int*    row_start = (int*)alloc((size_t)(N + 1) * 4);
    int*    partial   = (int*)alloc(256 * 4);
    float*  dinv      = (float*)alloc((size_t)N_PAD * 4);  // padded: epilogue reads rows < N_PAD
    int*    csr_src   = (int*)alloc((size_t)E * 4);
    bf16_t* h         = (bf16_t*)alloc((size_t)N_PAD * D_HID * 2);
    bf16_t* hw        = (bf16_t*)alloc((size_t)N_PAD * D_HID * 2);
    bf16_t* xb        = (bf16_t*)alloc((size_t)N_PAD * D_IN * 2);
    bf16_t* W1t       = (bf16_t*)alloc((size_t)D_HID * D_IN * 2);
    bf16_t* Wct       = (bf16_t*)alloc((size_t)N_LAYERS * D_HID * D_HID * 2);
    bf16_t* W2t       = (bf16_t*)alloc((size_t)D_OUT * D_HID * 2);

    hipMemsetAsync(deg, 0, (size_t)N * 4, stream);
    hipMemsetAsync(cursor, 0, (size_t)N * 4, stream);
    hipMemsetAsync(dinv + N, 0, (size_t)(N_PAD - N) * 4, stream);  // finite pad rowscale

    // conversions: x flat; weights transposed to [N][K]
    {
        int n = N * D_IN;
        f32_to_bf16<<<(n / 4 + 255) / 256, 256, 0, stream>>>(x, xb, n);
        dim3 tb(32, 8);
        transpose_to_bf16<<<dim3(D_HID / 32, D_IN / 32), tb, 0, stream>>>(W1, W1t, D_IN, D_HID);
        for (int i = 0; i < N_LAYERS; i++)
            transpose_to_bf16<<<dim3(D_HID / 32, D_HID / 32), tb, 0, stream>>>(
                Wc + (size_t)i * D_HID * D_HID, Wct + (size_t)i * D_HID * D_HID, D_HID, D_HID);
        transpose_to_bf16<<<dim3(D_OUT / 32, D_HID / 32), tb, 0, stream>>>(W2, W2t, D_HID, D_OUT);
    }

    // CSR build
    count_deg<<<(E + 255) / 256, 256, 0, stream>>>(ei + E, deg, E);
    const int nch = (N + 1023) / 1024;
    scan_reduce<<<nch, 256, 0, stream>>>(deg, partial, N);
    scan_partials<<<1, 64, 0, stream>>>(partial, nch, row_start, N, E);
    scan_chunks<<<nch, 1024, 0, stream>>>(deg, partial, row_start, N);
    compute_dinv<<<(N + 255) / 256, 256, 0, stream>>>(deg, dinv, N);
    fill_csr<<<(E + 255) / 256, 256, 0, stream>>>(ei, E, row_start, cursor, csr_src);

    const dim3 blk(256);
    const int mg = N_PAD / 128;  // 391

    // dnn1: h = relu(x @ W1 + b1)
    gemm_tile<false, true><<<dim3(D_HID / 128, mg), blk, 0, stream>>>(
        xb, W1t, b1, nullptr, h, N_PAD, D_HID, D_IN);

    // GCN layers: hw = dinv .* (h @ Wc[i]); h = dinv .* (hw[self] + gather-sum) + bc[i]
    for (int i = 0; i < N_LAYERS; i++) {
        gemm_tile<false, false><<<dim3(D_HID / 128, mg), blk, 0, stream>>>(
            h, Wct + (size_t)i * D_HID * D_HID, nullptr, dinv, hw, N_PAD, D_HID, D_HID);
        aggregate<<<(N + 3) / 4, 256, 0, stream>>>(hw, dinv, row_start, csr_src,
                                                   bc + (size_t)i * D_HID, h, N);
    }

    // dnn2: out = h @ W2 + b2 (fp32 out)
    gemm_tile<true, false><<<dim3(D_OUT / 128, mg), blk, 0, stream>>>(
        h, W2t, b2, nullptr, out, N, D_OUT, D_HID);
}

// Round 8
// 687.504 us; speedup vs baseline: 1.3069x; 1.1009x over previous
//
#include <hip/hip_runtime.h>

typedef __bf16 bf16_t;
typedef __bf16 bf16x8 __attribute__((ext_vector_type(8)));
typedef float f32x4 __attribute__((ext_vector_type(4)));
typedef float f32x2 __attribute__((ext_vector_type(2)));

#define N_NODES 50000
#define N_PAD   50048   // padded to multiple of 128 for 128-row GEMM tiles
#define N_EDGES 400000
#define D_IN    256
#define D_HID   512
#define D_OUT   128
#define N_LAYERS 4
#define ZROW    N_PAD                  // index of the always-zero hw row (dummy gathers)
#define CSR_CAP (N_EDGES + 3 * N_NODES + 64)  // padded-slot capacity

#define AS1 __attribute__((address_space(1)))
#define AS3 __attribute__((address_space(3)))

// ---------------- init: zero deg/cursor, dummy-fill csr, zero hw[ZROW], zero dinv pad ----

__global__ void init_misc(int* __restrict__ deg, int* __restrict__ cursor,
                          int* __restrict__ csr_src, float* __restrict__ dinv,
                          bf16_t* __restrict__ hw) {
    int idx = blockIdx.x * blockDim.x + threadIdx.x;
    if (idx < CSR_CAP) csr_src[idx] = ZROW;
    if (idx < N_NODES) { deg[idx] = 0; cursor[idx] = 0; }
    if (idx < N_PAD - N_NODES) dinv[N_NODES + idx] = 0.0f;
    if (idx < D_HID / 2) ((unsigned*)(hw + (size_t)ZROW * D_HID))[idx] = 0u;
}

// ---------------- fp32 -> bf16 conversion (flat, for x) ----------------

__global__ void f32_to_bf16(const float* __restrict__ in, bf16_t* __restrict__ out, int n) {
    int idx = (blockIdx.x * blockDim.x + threadIdx.x) * 4;
    if (idx + 3 < n) {
        float4 v = *reinterpret_cast<const float4*>(in + idx);
        bf16_t o[4] = {(bf16_t)v.x, (bf16_t)v.y, (bf16_t)v.z, (bf16_t)v.w};
        *reinterpret_cast<uint2*>(out + idx) = *reinterpret_cast<const uint2*>(o);
    } else {
        for (int j = idx; j < n; j++) out[j] = (bf16_t)in[j];
    }
}

// ---------------- batched fp32 [R][C] -> bf16 transposed [C][R] for all weights --------
// z: 0 = W1 (256x512), 1..4 = Wc layer (512x512), 5 = W2 (512x128)

__global__ void transpose_all(const float* __restrict__ W1, const float* __restrict__ Wc,
                              const float* __restrict__ W2, bf16_t* __restrict__ W1t,
                              bf16_t* __restrict__ Wct, bf16_t* __restrict__ W2t) {
    const float* in; bf16_t* out; int R, C;
    const int z = blockIdx.z;
    if (z == 0)      { in = W1; out = W1t; R = D_IN;  C = D_HID; }
    else if (z <= 4) { in = Wc + (size_t)(z - 1) * D_HID * D_HID;
                       out = Wct + (size_t)(z - 1) * D_HID * D_HID; R = D_HID; C = D_HID; }
    else             { in = W2; out = W2t; R = D_HID; C = D_OUT; }

    const int c0 = blockIdx.x * 32;
    const int r0 = blockIdx.y * 32;
    if (c0 >= C || r0 >= R) return;
    __shared__ float tile[32][33];
    for (int i = threadIdx.y; i < 32; i += 8)
        tile[i][threadIdx.x] = in[(size_t)(r0 + i) * C + c0 + threadIdx.x];
    __syncthreads();
    for (int i = threadIdx.y; i < 32; i += 8)
        out[(size_t)(c0 + i) * R + r0 + threadIdx.x] = (bf16_t)tile[threadIdx.x][i];
}

// ---------------- degree / padded CSR build ----------------

__global__ void count_deg(const int* __restrict__ dst, int* __restrict__ deg, int E) {
    int e = blockIdx.x * blockDim.x + threadIdx.x;
    if (e < E) atomicAdd(&deg[dst[e]], 1);
}

__global__ void scan_reduce(const int* __restrict__ deg, int* __restrict__ partial, int N) {
    __shared__ int red[256];
    int base = blockIdx.x * 1024;
    int s = 0;
    for (int i = threadIdx.x; i < 1024; i += 256) {
        int idx = base + i;
        s += (idx < N) ? ((deg[idx] + 3) & ~3) : 0;   // padded slots
    }
    red[threadIdx.x] = s;
    __syncthreads();
    for (int off = 128; off > 0; off >>= 1) {
        if (threadIdx.x < off) red[threadIdx.x] += red[threadIdx.x + off];
        __syncthreads();
    }
    if (threadIdx.x == 0) partial[blockIdx.x] = red[0];
}

__global__ void scan_partials(int* __restrict__ partial, int nb,
                              int* __restrict__ row_start, int N) {
    if (threadIdx.x == 0 && blockIdx.x == 0) {
        int acc = 0;
        for (int i = 0; i < nb; i++) { int v = partial[i]; partial[i] = acc; acc += v; }
        row_start[N] = acc;   // total padded slots
    }
}

__global__ void scan_chunks(const int* __restrict__ deg, const int* __restrict__ partial,
                            int* __restrict__ row_start, float* __restrict__ dinv, int N) {
    __shared__ int buf[2][1024];
    int t = threadIdx.x;
    int gid = blockIdx.x * 1024 + t;
    int d = (gid < N) ? deg[gid] : 0;
    int v = (gid < N) ? ((d + 3) & ~3) : 0;           // padded slots
    int cur = 0;
    buf[0][t] = v;
    __syncthreads();
    for (int off = 1; off < 1024; off <<= 1) {
        int nxt = cur ^ 1;
        int val = buf[cur][t];
        if (t >= off) val += buf[cur][t - off];
        buf[nxt][t] = val;
        cur = nxt;
        __syncthreads();
    }
    int incl = buf[cur][t];
    if (gid < N) {
        row_start[gid] = partial[blockIdx.x] + incl - v;  // exclusive
        dinv[gid] = rsqrtf((float)(d + 1));               // +1 self loop
    }
}

__global__ void fill_csr(const int* __restrict__ ei, int E,
                         const int* __restrict__ row_start,
                         int* __restrict__ cursor, int* __restrict__ csr_src) {
    int e = blockIdx.x * blockDim.x + threadIdx.x;
    if (e < E) {
        int s = ei[e];
        int d = ei[E + e];
        int pos = atomicAdd(&cursor[d], 1);
        csr_src[row_start[d] + pos] = s;
    }
}

// ---------------- GEMM: C = act(rowscale * (A @ BT^T) + bias) ----------------
// A: [M_pad][K] bf16. BT: [N][K] bf16 (pre-transposed). Block tile 128 x 128,
// 4 waves each 64x64 (acc 64 f32 -> AGPR), BK=64, global_load_lds width=16.
// LDS XOR-swizzled (chunk c of row r holds k-group c^(r&7)): conflict-free reads.
// XCD swizzle (gridDim.x==4): the 4 blocks sharing A-rows get ids == same (mod 8)
// so they land on the same XCD L2 -> A fetched into 1 L2 instead of 4.

template <bool F32OUT, bool RELU>
__global__ __launch_bounds__(256, 4) void gemm_tile(
    const bf16_t* __restrict__ A, const bf16_t* __restrict__ BT,
    const float* __restrict__ bias, const float* __restrict__ rowscale,
    void* __restrict__ Cv, int M, int N, int K)
{
    __shared__ __align__(16) char smem[32768];  // sA 16KB + sB 16KB; epilogue reuse
    bf16_t* sA = (bf16_t*)smem;
    bf16_t* sB = (bf16_t*)(smem + 128 * 128);
    bf16_t* sC = (bf16_t*)smem;                 // 64 x 136 bf16 = 17.4 KB

    int bxi, byi;
    if (gridDim.x == 4) {
        const int bid = blockIdx.y * 4 + blockIdx.x;     // dispatch-linear id
        const int T0 = (int)(gridDim.y * 4) & ~31;
        if (bid < T0) { int q = bid >> 5, r = bid & 31; byi = q * 8 + (r & 7); bxi = r >> 3; }
        else          { int t = bid - T0; byi = (T0 >> 2) + (t >> 2); bxi = t & 3; }
    } else { bxi = blockIdx.x; byi = blockIdx.y; }

    const int tid  = threadIdx.x;
    const int lane = tid & 63;
    const int wave = tid >> 6;
    const int bn = bxi * 128;
    const int bm = byi * 128;
    const int wm = (wave & 1) * 64;
    const int wn = (wave >> 1) * 64;
    const int lm = lane & 15;
    const int lq = lane >> 4;

    // staging: each 1KB wave-load covers 8 rows x 8 chunks; lane (r8,c8)
    const int r8 = lane >> 3;
    const int c8 = lane & 7;
    const int ksw = (c8 ^ r8) * 8;              // swizzled k-offset (elements)

    f32x4 acc[4][4] = {};

    const int nkb = K >> 6;
    for (int kb = 0; kb < nkb; kb++) {
        const int k0 = kb * 64;
#pragma unroll
        for (int r = 0; r < 4; r++) {               // A: 16 groups of 8 rows
            const int g = r * 4 + wave;
            __builtin_amdgcn_global_load_lds(
                (const AS1 unsigned int*)(A + (size_t)(bm + g * 8 + r8) * K + k0 + ksw),
                (AS3 unsigned int*)((AS3 char*)(AS3 bf16_t*)sA + g * 1024),
                16, 0, 0);
        }
#pragma unroll
        for (int r = 0; r < 4; r++) {               // B: 16 groups of 8 rows
            const int g = r * 4 + wave;
            __builtin_amdgcn_global_load_lds(
                (const AS1 unsigned int*)(BT + (size_t)(bn + g * 8 + r8) * K + k0 + ksw),
                (AS3 unsigned int*)((AS3 char*)(AS3 bf16_t*)sB + g * 1024),
                16, 0, 0);
        }
        __syncthreads();

#pragma unroll
        for (int s = 0; s < 2; s++) {               // two K=32 steps per BK=64
            bf16x8 af[4], bfr[4];
#pragma unroll
            for (int mt = 0; mt < 4; mt++) {
                const int R = wm + mt * 16 + lm;
                const int g = s * 4 + lq;
                af[mt] = *reinterpret_cast<bf16x8*>(&sA[R * 64 + ((g ^ (R & 7)) * 8)]);
            }
#pragma unroll
            for (int nt = 0; nt < 4; nt++) {
                const int R = wn + nt * 16 + lm;
                const int g = s * 4 + lq;
                bfr[nt] = *reinterpret_cast<bf16x8*>(&sB[R * 64 + ((g ^ (R & 7)) * 8)]);
            }
#pragma unroll
            for (int mt = 0; mt < 4; mt++)
#pragma unroll
                for (int nt = 0; nt < 4; nt++)
                    acc[mt][nt] = __builtin_amdgcn_mfma_f32_16x16x32_bf16(af[mt], bfr[nt], acc[mt][nt], 0, 0, 0);
        }
        __syncthreads();
    }

    if (!F32OUT) {
        // coalesced epilogue: 2 passes of 64 rows through LDS; sC row stride 136 elems
        const size_t rowbytes = (size_t)N * 2;
#pragma unroll
        for (int p = 0; p < 2; p++) {
            if (p) __syncthreads();
            if ((wave & 1) == p) {
#pragma unroll
                for (int nt = 0; nt < 4; nt++) {
                    const int col = wn + nt * 16 + lm;
                    const float bv = bias ? bias[bn + col] : 0.0f;
#pragma unroll
                    for (int mt = 0; mt < 4; mt++) {
#pragma unroll
                        for (int r = 0; r < 4; r++) {
                            const int lrow = mt * 16 + lq * 4 + r;
                            float v = acc[mt][nt][r] + bv;
                            if (rowscale) v *= rowscale[bm + p * 64 + lrow];
                            if (RELU) v = fmaxf(v, 0.0f);
                            sC[lrow * 136 + col] = (bf16_t)v;
                        }
                    }
                }
            }
            __syncthreads();
            char* outbase = (char*)Cv + (size_t)(bm + p * 64) * rowbytes + (size_t)bn * 2;
#pragma unroll
            for (int j = 0; j < 4; j++) {
                const int idx = j * 4096 + tid * 16;
                const int row = idx >> 8;            // 256 data bytes per row
                const int colb = idx & 255;
                *reinterpret_cast<uint4*>(outbase + (size_t)row * rowbytes + colb) =
                    *reinterpret_cast<const uint4*>((char*)sC + (size_t)row * 272 + colb);
            }
        }
    } else {
        // scattered epilogue (dnn2, fp32 out): C/D layout col=lane&15, row=lq*4+reg
#pragma unroll
        for (int nt = 0; nt < 4; nt++) {
            const int col = bn + wn + nt * 16 + lm;
            const float bv = bias ? bias[col] : 0.0f;
#pragma unroll
            for (int mt = 0; mt < 4; mt++) {
#pragma unroll
                for (int r = 0; r < 4; r++) {
                    const int row = bm + wm + mt * 16 + lq * 4 + r;
                    if (row < M) {
                        float v = acc[mt][nt][r] + bv;
                        if (rowscale) v *= rowscale[row];
                        if (RELU) v = fmaxf(v, 0.0f);
                        ((float*)Cv)[(size_t)row * N + col] = v;
                    }
                }
            }
        }
    }
}

// ---------------- aggregation ----------------
// hw is pre-scaled: hw[s] = dinv[s] * (h W)[s]. Slots padded to x4, dummies -> ZROW (zeros).
// h_out[n] = dinv[n] * ( hw[n] + sum_slots hw[s] ) + bias
// one wave per node; lane handles 8 contiguous features (512 = 64*8).
// Main loop: 8 slots/iter -> 2 int4 index loads + 8 independent 16B gathers in flight.
// Accumulate as float2 (lo = u<<16, hi = u & 0xffff0000) -> v_pk_add_f32.

__global__ __launch_bounds__(256) void aggregate(
    const bf16_t* __restrict__ hw, const float* __restrict__ dinv,
    const int* __restrict__ row_start, const int* __restrict__ csr_src,
    const float* __restrict__ bias, bf16_t* __restrict__ h_out, int N)
{
    const int n = blockIdx.x * 4 + (threadIdx.x >> 6);
    const int lane = threadIdx.x & 63;
    if (n >= N) return;

    const float dn = dinv[n];
    const char* hwb = (const char*)hw + lane * 16;

    f32x2 acc[4];
    {   // self term (already scaled by dinv[n])
        uint4 u = *reinterpret_cast<const uint4*>(hwb + ((size_t)n << 10));
        const unsigned* w = reinterpret_cast<const unsigned*>(&u);
#pragma unroll
        for (int j = 0; j < 4; j++) {
            acc[j][0] = __uint_as_float(w[j] << 16);
            acc[j][1] = __uint_as_float(w[j] & 0xffff0000u);
        }
    }

    const int beg = row_start[n];
    const int cnt = row_start[n + 1] - beg;      // multiple of 4
    const int* ip = csr_src + beg;               // 16B-aligned (beg multiple of 4)

    int i = 0;
    for (; i + 8 <= cnt; i += 8) {
        const int4 a = *reinterpret_cast<const int4*>(ip + i);
        const int4 b = *reinterpret_cast<const int4*>(ip + i + 4);
        uint4 u[8];
        u[0] = *reinterpret_cast<const uint4*>(hwb + ((size_t)a.x << 10));
        u[1] = *reinterpret_cast<const uint4*>(hwb + ((size_t)a.y << 10));
        u[2] = *reinterpret_cast<const uint4*>(hwb + ((size_t)a.z << 10));
        u[3] = *reinterpret_cast<const uint4*>(hwb + ((size_t)a.w << 10));
        u[4] = *reinterpret_cast<const uint4*>(hwb + ((size_t)b.x << 10));
        u[5] = *reinterpret_cast<const uint4*>(hwb + ((size_t)b.y << 10));
        u[6] = *reinterpret_cast<const uint4*>(hwb + ((size_t)b.z << 10));
        u[7] = *reinterpret_cast<const uint4*>(hwb + ((size_t)b.w << 10));
#pragma unroll
        for (int q = 0; q < 8; q++) {
            const unsigned* w = reinterpret_cast<const unsigned*>(&u[q]);
#pragma unroll
            for (int j = 0; j < 4; j++) {
                f32x2 v;
                v[0] = __uint_as_float(w[j] << 16);
                v[1] = __uint_as_float(w[j] & 0xffff0000u);
                acc[j] += v;
            }
        }
    }
    if (i < cnt) {                               // one final 4-slot chunk
        const int4 a = *reinterpret_cast<const int4*>(ip + i);
        uint4 u[4];
        u[0] = *reinterpret_cast<const uint4*>(hwb + ((size_t)a.x << 10));
        u[1] = *reinterpret_cast<const uint4*>(hwb + ((size_t)a.y << 10));
        u[2] = *reinterpret_cast<const uint4*>(hwb + ((size_t)a.z << 10));
        u[3] = *reinterpret_cast<const uint4*>(hwb + ((size_t)a.w << 10));
#pragma unroll
        for (int q = 0; q < 4; q++) {
            const unsigned* w = reinterpret_cast<const unsigned*>(&u[q]);
#pragma unroll
            for (int j = 0; j < 4; j++) {
                f32x2 v;
                v[0] = __uint_as_float(w[j] << 16);
                v[1] = __uint_as_float(w[j] & 0xffff0000u);
                acc[j] += v;
            }
        }
    }

    const int f = lane * 8;
    bf16_t outv[8];
#pragma unroll
    for (int j = 0; j < 4; j++) {
        outv[2 * j]     = (bf16_t)(fmaf(dn, acc[j][0], bias[f + 2 * j]));
        outv[2 * j + 1] = (bf16_t)(fmaf(dn, acc[j][1], bias[f + 2 * j + 1]));
    }
    *reinterpret_cast<uint4*>(h_out + (size_t)n * D_HID + f) = *reinterpret_cast<const uint4*>(outv);
}

// ---------------- orchestration ----------------

extern "C" void kernel_launch(void* const* d_in, const int* in_sizes, int n_in,
                              void* d_out, int out_size, void* d_ws, size_t ws_size,
                              hipStream_t stream) {
    const int N = N_NODES, E = N_EDGES;

    const float* x  = (const float*)d_in[0];
    const int*   ei = (const int*)d_in[1];
    const float* W1 = (const float*)d_in[2];
    const float* b1 = (const float*)d_in[3];
    const float* Wc = (const float*)d_in[4];
    const float* bc = (const float*)d_in[5];
    const float* W2 = (const float*)d_in[6];
    const float* b2 = (const float*)d_in[7];
    float* out = (float*)d_out;

    char* ws = (char*)d_ws;
    size_t off = 0;
    auto alloc = [&](size_t bytes) -> void* {
        void* p = ws + off;
        off += (bytes + 255) & ~(size_t)255;
        return p;
    };
    int*    deg       = (int*)alloc((size_t)N * 4);
    int*    cursor    = (int*)alloc((size_t)N * 4);
    int*    row_start = (int*)alloc((size_t)(N + 1) * 4);
    int*    partial   = (int*)alloc(256 * 4);
    float*  dinv      = (float*)alloc((size_t)N_PAD * 4);
    int*    csr_src   = (int*)alloc((size_t)CSR_CAP * 4);
    bf16_t* h         = (bf16_t*)alloc((size_t)N_PAD * D_HID * 2);
    bf16_t* hw        = (bf16_t*)alloc((size_t)(N_PAD + 1) * D_HID * 2);  // +1: ZROW
    bf16_t* xb        = (bf16_t*)alloc((size_t)N_PAD * D_IN * 2);
    bf16_t* W1t       = (bf16_t*)alloc((size_t)D_HID * D_IN * 2);
    bf16_t* Wct       = (bf16_t*)alloc((size_t)N_LAYERS * D_HID * D_HID * 2);
    bf16_t* W2t       = (bf16_t*)alloc((size_t)D_OUT * D_HID * 2);

    // init (zero deg/cursor, dummy csr fill, zero hw[ZROW], zero dinv pad)
    init_misc<<<(CSR_CAP + 255) / 256, 256, 0, stream>>>(deg, cursor, csr_src, dinv, hw);

    // conversions
    {
        int n = N * D_IN;
        f32_to_bf16<<<(n / 4 + 255) / 256, 256, 0, stream>>>(x, xb, n);
        transpose_all<<<dim3(16, 16, 6), dim3(32, 8), 0, stream>>>(W1, Wc, W2, W1t, Wct, W2t);
    }

    // padded CSR build
    count_deg<<<(E + 255) / 256, 256, 0, stream>>>(ei + E, deg, E);
    const int nch = (N + 1023) / 1024;
    scan_reduce<<<nch, 256, 0, stream>>>(deg, partial, N);
    scan_partials<<<1, 64, 0, stream>>>(partial, nch, row_start, N);
    scan_chunks<<<nch, 1024, 0, stream>>>(deg, partial, row_start, dinv, N);
    fill_csr<<<(E + 255) / 256, 256, 0, stream>>>(ei, E, row_start, cursor, csr_src);

    const dim3 blk(256);
    const int mg = N_PAD / 128;  // 391

    // dnn1: h = relu(x @ W1 + b1)
    gemm_tile<false, true><<<dim3(D_HID / 128, mg), blk, 0, stream>>>(
        xb, W1t, b1, nullptr, h, N_PAD, D_HID, D_IN);

    // GCN layers: hw = dinv .* (h @ Wc[i]); h = dinv .* (hw[self] + gather-sum) + bc[i]
    for (int i = 0; i < N_LAYERS; i++) {
        gemm_tile<false, false><<<dim3(D_HID / 128, mg), blk, 0, stream>>>(
            h, Wct + (size_t)i * D_HID * D_HID, nullptr, dinv, hw, N_PAD, D_HID, D_HID);
        aggregate<<<(N + 3) / 4, 256, 0, stream>>>(hw, dinv, row_start, csr_src,
                                                   bc + (size_t)i * D_HID, h, N);
    }

    // dnn2: out = h @ W2 + b2 (fp32 out)
    gemm_tile<true, false><<<dim3(D_OUT / 128, mg), blk, 0, stream>>>(
        h, W2t, b2, nullptr, out, N, D_OUT, D_HID);
}